// Round 2
// baseline (3651.555 us; speedup 1.0000x reference)
//
#include <hip/hip_runtime.h>

// PairNetLayer_symmetry: N=512 nodes, E=262144 edges. ALL float tensors are f32
// (per reference setup_inputs: jnp.float32); dst/src int32; output f32.
// Stage 1 (node_kernel): na0 = e3_linear(node_attr, W_inner*), h = e3_linear(norm_gate(node_attr, gp_*), W_in*)
//   -> f32 tables in d_ws (512x320 each, L2-resident).
// Stage 2 (edge_kernel): fully fused per-edge pipeline, 16 edges/block, VALU matmuls.

#define N_NODES 512
#define E_EDGES 262144
#define M0 128
#define M1 64
#define MT0 192
#define WN 256
#define EAw 32
#define INVw 8
#define TE 16

__device__ __forceinline__ float siluf(float x) { return x / (1.f + __expf(-x)); }
__device__ __forceinline__ float sspf(float x) {
  // softplus(x) - ln(2), overflow-safe
  return fmaxf(x, 0.f) + log1pf(__expf(-fabsf(x))) - 0.6931471805599453f;
}

#define RS128 0.08838834764831845f
#define RS192 0.07216878364870323f
#define RS64  0.125f
#define RS32  0.17677669529663687f
#define RS8   0.35355339059327373f
#define RS3   0.5773502691896258f
#define RS2   0.7071067811865476f

__global__ __launch_bounds__(192) void node_kernel(
    const float* __restrict__ node_attr,
    const float* __restrict__ W_inner0, const float* __restrict__ b_inner0, const float* __restrict__ W_inner1,
    const float* __restrict__ W_in0, const float* __restrict__ b_in0, const float* __restrict__ W_in1,
    const float* __restrict__ gp_W1, const float* __restrict__ gp_b1,
    const float* __restrict__ gp_W2, const float* __restrict__ gp_b2,
    float* __restrict__ na0_tab, float* __restrict__ h_tab)
{
  const int node = blockIdx.x;
  const int t = threadIdx.x;
  __shared__ float x[320];
  __shared__ float cat[MT0];
  __shared__ float g1[MT0];
  __shared__ float g[MT0];
  __shared__ float hh[320];

  for (int i = t; i < 320; i += 192) x[i] = node_attr[node * 320 + i];
  __syncthreads();

  // ---- na0 = e3_linear(x, W_inner0/sqrt(128), b_inner0, W_inner1/8) ----
  {
    if (t < M0) {
      float acc = 0.f;
      for (int k = 0; k < M0; ++k) acc += x[k] * W_inner0[k * M0 + t];
      na0_tab[node * 320 + t] = acc * RS128 + b_inner0[t];
    }
    int vv = t / 3, ii = t - 3 * vv;
    float acc = 0.f;
    for (int u = 0; u < M1; ++u) acc += x[M0 + 3 * u + ii] * W_inner1[u * M1 + vv];
    na0_tab[node * 320 + M0 + t] = acc * RS64;
  }

  // ---- norm_gate(x, gp_*) ----
  if (t < M0) cat[t] = x[t];
  if (t < M1) {
    float a = x[M0 + 3 * t], b = x[M0 + 3 * t + 1], c = x[M0 + 3 * t + 2];
    cat[M0 + t] = sqrtf(a * a + b * b + c * c + 1e-12f);
  }
  __syncthreads();
  {
    float acc = 0.f;
    for (int k = 0; k < MT0; ++k) acc += cat[k] * gp_W1[k * MT0 + t];
    g1[t] = siluf(acc + gp_b1[t]);
  }
  __syncthreads();
  {
    float acc = 0.f;
    for (int k = 0; k < MT0; ++k) acc += g1[k] * gp_W2[k * MT0 + t];
    g[t] = acc + gp_b2[t];
  }
  __syncthreads();
  if (t < M0) hh[t] = g[t];
  hh[M0 + t] = x[M0 + t] * g[M0 + t / 3];
  __syncthreads();

  // ---- h = e3_linear(hh, W_in0/sqrt(128), b_in0, W_in1/8) ----
  {
    if (t < M0) {
      float acc = 0.f;
      for (int k = 0; k < M0; ++k) acc += hh[k] * W_in0[k * M0 + t];
      h_tab[node * 320 + t] = acc * RS128 + b_in0[t];
    }
    int vv = t / 3, ii = t - 3 * vv;
    float acc = 0.f;
    for (int u = 0; u < M1; ++u) acc += hh[M0 + 3 * u + ii] * W_in1[u * M1 + vv];
    h_tab[node * 320 + M0 + t] = acc * RS64;
  }
}

__global__ __launch_bounds__(256) void edge_kernel(
    const float* __restrict__ edge_attr, const float* __restrict__ node_pair_attr,
    const float* __restrict__ fcnp_W1, const float* __restrict__ fcnp_W2,
    const float* __restrict__ fcs_W1, const float* __restrict__ fcs_b1,
    const float* __restrict__ fcs_W2, const float* __restrict__ fcs_b2,
    const float* __restrict__ ng_W1, const float* __restrict__ ng_b1,
    const float* __restrict__ ng_W2, const float* __restrict__ ng_b2,
    const float* __restrict__ res_W0, const float* __restrict__ res_b0,
    const float* __restrict__ res_W1,
    const int* __restrict__ dst, const int* __restrict__ src,
    const float* __restrict__ na0_tab, const float* __restrict__ h_tab,
    float* __restrict__ out)
{
  const int e0 = blockIdx.x * TE;
  const int t = threadIdx.x;

  // buffer lifetimes: bufA: s0 -> w -> cat -> g ; bufB: t1 -> g1 ; bufP: pair -> pair2 -> out
  __shared__ __align__(16) float bufA[TE][WN];
  __shared__ __align__(16) float bufB[TE][WN];
  __shared__ __align__(16) float bufP[TE][384];
  __shared__ float pbuf[TE][INVw];
  __shared__ int di[TE], si[TE];

  if (t < TE) { di[t] = dst[e0 + t]; si[t] = src[e0 + t]; }
  __syncthreads();

  // ---- s0 into bufA[:,:192] ----
  for (int idx = t; idx < TE * MT0; idx += 256) {
    int e = idx / MT0, j = idx - e * MT0;
    const float* rd = na0_tab + di[e] * 320;
    const float* rs = na0_tab + si[e] * 320;
    float v;
    if (j < M0) {
      v = 0.5f * (rd[j] + rs[j]);
    } else {
      int u = j - M0;
      v = (rd[M0 + 3 * u] * rs[M0 + 3 * u] + rd[M0 + 3 * u + 1] * rs[M0 + 3 * u + 1] +
           rd[M0 + 3 * u + 2] * rs[M0 + 3 * u + 2]) * RS3;
    }
    bufA[e][j] = v;
  }
  // ---- w_edge inner: pbuf = ssp(edge_attr @ fcnp_W1 / sqrt(32)) ----
  if (t < TE * INVw) {
    int e = t / INVw, m = t - (t / INVw) * INVw;
    const float* ea = edge_attr + (size_t)(e0 + e) * EAw;
    float acc = 0.f;
    for (int k = 0; k < EAw; ++k) acc += ea[k] * fcnp_W1[k * INVw + m];
    pbuf[e][m] = sspf(acc * RS32);
  }
  __syncthreads();

  // ---- M1: t1 = silu(s0 @ fcs_W1 + b1) -> bufB[:,:128] ----
  {
    int j = t & 127, eg = t >> 7;
    float acc[8];
#pragma unroll
    for (int ee = 0; ee < 8; ++ee) acc[ee] = 0.f;
    for (int k = 0; k < MT0; k += 4) {
      float w0 = fcs_W1[(k + 0) * M0 + j];
      float w1 = fcs_W1[(k + 1) * M0 + j];
      float w2 = fcs_W1[(k + 2) * M0 + j];
      float w3 = fcs_W1[(k + 3) * M0 + j];
#pragma unroll
      for (int ee = 0; ee < 8; ++ee) {
        float4 v = *reinterpret_cast<const float4*>(&bufA[eg * 8 + ee][k]);
        acc[ee] = fmaf(v.x, w0, fmaf(v.y, w1, fmaf(v.z, w2, fmaf(v.w, w3, acc[ee]))));
      }
    }
    float b = fcs_b1[j];
#pragma unroll
    for (int ee = 0; ee < 8; ++ee) bufB[eg * 8 + ee][j] = siluf(acc[ee] + b);
  }
  __syncthreads();

  // ---- M2: w = (t1 @ fcs_W2 + b2) * (pbuf @ fcnp_W2/sqrt(8)) -> bufA ----
  {
    int j = t;
    float acc[TE];
#pragma unroll
    for (int e = 0; e < TE; ++e) acc[e] = 0.f;
    for (int k = 0; k < M0; k += 4) {
      float w0 = fcs_W2[(k + 0) * WN + j];
      float w1 = fcs_W2[(k + 1) * WN + j];
      float w2 = fcs_W2[(k + 2) * WN + j];
      float w3 = fcs_W2[(k + 3) * WN + j];
#pragma unroll
      for (int e = 0; e < TE; ++e) {
        float4 v = *reinterpret_cast<const float4*>(&bufB[e][k]);
        acc[e] = fmaf(v.x, w0, fmaf(v.y, w1, fmaf(v.z, w2, fmaf(v.w, w3, acc[e]))));
      }
    }
    float b = fcs_b2[j];
    float wm[INVw];
#pragma unroll
    for (int m = 0; m < INVw; ++m) wm[m] = fcnp_W2[m * WN + j] * RS8;
#pragma unroll
    for (int e = 0; e < TE; ++e) {
      float we = 0.f;
#pragma unroll
      for (int m = 0; m < INVw; ++m) we += pbuf[e][m] * wm[m];
      bufA[e][j] = (acc[e] + b) * we;
    }
  }
  __syncthreads();

  // ---- pair into bufP (reads w=bufA, h tables) ----
  for (int idx = t; idx < TE * 384; idx += 256) {
    int e = idx / 384, j = idx - e * 384;
    const float* hd = h_tab + di[e] * 320;
    const float* hs = h_tab + si[e] * 320;
    float v;
    if (j < M0) {
      v = bufA[e][j] * hs[j] * hd[j];
    } else if (j < MT0) {
      int u = j - M0;
      v = bufA[e][j] * RS3 *
          (hs[M0 + 3 * u] * hd[M0 + 3 * u] + hs[M0 + 3 * u + 1] * hd[M0 + 3 * u + 1] +
           hs[M0 + 3 * u + 2] * hd[M0 + 3 * u + 2]);
    } else {
      int c = j - MT0;
      int u = c / 3, ii = c - 3 * u;
      int i1 = ii == 2 ? 0 : ii + 1;
      int i2 = i1 == 2 ? 0 : i1 + 1;
      float a1 = hs[M0 + 3 * u + i1], a2 = hs[M0 + 3 * u + i2];
      float b1 = hd[M0 + 3 * u + i1], b2 = hd[M0 + 3 * u + i2];
      v = bufA[e][MT0 + u] * RS2 * (a1 * b2 - a2 * b1);  // (xs x xd)_ii
    }
    bufP[e][j] = v;
  }
  __syncthreads();

  // ---- ng cat = [pair[:192], norms(pair_v)] -> bufA ----
  for (int idx = t; idx < TE * WN; idx += 256) {
    int e = idx >> 8, j = idx & 255;
    float v;
    if (j < MT0) {
      v = bufP[e][j];
    } else {
      int u = j - MT0;
      float a = bufP[e][MT0 + 3 * u], b = bufP[e][MT0 + 3 * u + 1], c = bufP[e][MT0 + 3 * u + 2];
      v = sqrtf(a * a + b * b + c * c + 1e-12f);
    }
    bufA[e][j] = v;
  }
  __syncthreads();

  // ---- M3: g1 = silu(cat @ ng_W1 + b1) -> bufB ----
  {
    int j = t;
    float acc[TE];
#pragma unroll
    for (int e = 0; e < TE; ++e) acc[e] = 0.f;
    for (int k = 0; k < WN; k += 4) {
      float w0 = ng_W1[(k + 0) * WN + j];
      float w1 = ng_W1[(k + 1) * WN + j];
      float w2 = ng_W1[(k + 2) * WN + j];
      float w3 = ng_W1[(k + 3) * WN + j];
#pragma unroll
      for (int e = 0; e < TE; ++e) {
        float4 v = *reinterpret_cast<const float4*>(&bufA[e][k]);
        acc[e] = fmaf(v.x, w0, fmaf(v.y, w1, fmaf(v.z, w2, fmaf(v.w, w3, acc[e]))));
      }
    }
    float b = ng_b1[j];
#pragma unroll
    for (int e = 0; e < TE; ++e) bufB[e][j] = siluf(acc[e] + b);
  }
  __syncthreads();

  // ---- M4: g = g1 @ ng_W2 + b2 -> bufA ----
  {
    int j = t;
    float acc[TE];
#pragma unroll
    for (int e = 0; e < TE; ++e) acc[e] = 0.f;
    for (int k = 0; k < WN; k += 4) {
      float w0 = ng_W2[(k + 0) * WN + j];
      float w1 = ng_W2[(k + 1) * WN + j];
      float w2 = ng_W2[(k + 2) * WN + j];
      float w3 = ng_W2[(k + 3) * WN + j];
#pragma unroll
      for (int e = 0; e < TE; ++e) {
        float4 v = *reinterpret_cast<const float4*>(&bufB[e][k]);
        acc[e] = fmaf(v.x, w0, fmaf(v.y, w1, fmaf(v.z, w2, fmaf(v.w, w3, acc[e]))));
      }
    }
    float b = ng_b2[j];
#pragma unroll
    for (int e = 0; e < TE; ++e) bufA[e][j] = acc[e] + b;
  }
  __syncthreads();

  // ---- pair2 in place: s <- g[:192]; v <- v * g[192+u] ----
  for (int idx = t; idx < TE * 384; idx += 256) {
    int e = idx / 384, j = idx - e * 384;
    if (j < MT0) bufP[e][j] = bufA[e][j];
    else bufP[e][j] *= bufA[e][MT0 + (j - MT0) / 3];
  }
  __syncthreads();

  // ---- M5: out_s = pair2[:192] @ res_W0/sqrt(192) + res_b0 ----
  float outs[8];
  const int j5 = t & 127, eg5 = t >> 7;
  {
    float acc[8];
#pragma unroll
    for (int ee = 0; ee < 8; ++ee) acc[ee] = 0.f;
    for (int k = 0; k < MT0; k += 4) {
      float w0 = res_W0[(k + 0) * M0 + j5];
      float w1 = res_W0[(k + 1) * M0 + j5];
      float w2 = res_W0[(k + 2) * M0 + j5];
      float w3 = res_W0[(k + 3) * M0 + j5];
#pragma unroll
      for (int ee = 0; ee < 8; ++ee) {
        float4 v = *reinterpret_cast<const float4*>(&bufP[eg5 * 8 + ee][k]);
        acc[ee] = fmaf(v.x, w0, fmaf(v.y, w1, fmaf(v.z, w2, fmaf(v.w, w3, acc[ee]))));
      }
    }
    float b = res_b0[j5];
#pragma unroll
    for (int ee = 0; ee < 8; ++ee) outs[ee] = acc[ee] * RS192 + b;
  }

  // ---- M6: out_v = einsum(pair2_v, res_W1)/8 ----
  float outv[TE];
  if (t < MT0) {
    int vv = t / 3, ii = t - 3 * vv;
    float acc[TE];
#pragma unroll
    for (int e = 0; e < TE; ++e) acc[e] = 0.f;
    for (int u = 0; u < M1; ++u) {
      float wv = res_W1[u * M1 + vv];
#pragma unroll
      for (int e = 0; e < TE; ++e) acc[e] += bufP[e][MT0 + 3 * u + ii] * wv;
    }
#pragma unroll
    for (int e = 0; e < TE; ++e) outv[e] = acc[e] * RS64;
  }
  __syncthreads();

  // ---- write outputs into bufP[:, :320] ----
#pragma unroll
  for (int ee = 0; ee < 8; ++ee) bufP[eg5 * 8 + ee][j5] = outs[ee];
  if (t < MT0) {
#pragma unroll
    for (int e = 0; e < TE; ++e) bufP[e][M0 + t] = outv[e];
  }
  __syncthreads();

  // ---- final: out = bufP + node_pair_attr ----
  for (int idx = t; idx < TE * 320; idx += 256) {
    int e = idx / 320, j = idx - e * 320;
    size_t off = (size_t)(e0 + e) * 320 + j;
    out[off] = bufP[e][j] + node_pair_attr[off];
  }
}

extern "C" void kernel_launch(void* const* d_in, const int* in_sizes, int n_in,
                              void* d_out, int out_size, void* d_ws, size_t ws_size,
                              hipStream_t stream) {
  const float* node_attr      = (const float*)d_in[0];
  const float* edge_attr      = (const float*)d_in[1];
  const float* node_pair_attr = (const float*)d_in[2];
  const float* W_inner0 = (const float*)d_in[3];
  const float* b_inner0 = (const float*)d_in[4];
  const float* W_inner1 = (const float*)d_in[5];
  const float* W_in0    = (const float*)d_in[6];
  const float* b_in0    = (const float*)d_in[7];
  const float* W_in1    = (const float*)d_in[8];
  const float* gp_W1    = (const float*)d_in[9];
  const float* gp_b1    = (const float*)d_in[10];
  const float* gp_W2    = (const float*)d_in[11];
  const float* gp_b2    = (const float*)d_in[12];
  const float* fcnp_W1  = (const float*)d_in[13];
  const float* fcnp_W2  = (const float*)d_in[14];
  const float* fcs_W1   = (const float*)d_in[15];
  const float* fcs_b1   = (const float*)d_in[16];
  const float* fcs_W2   = (const float*)d_in[17];
  const float* fcs_b2   = (const float*)d_in[18];
  const float* ng_W1    = (const float*)d_in[19];
  const float* ng_b1    = (const float*)d_in[20];
  const float* ng_W2    = (const float*)d_in[21];
  const float* ng_b2    = (const float*)d_in[22];
  const float* res_W0   = (const float*)d_in[23];
  const float* res_b0   = (const float*)d_in[24];
  const float* res_W1   = (const float*)d_in[25];
  const int* dst = (const int*)d_in[26];
  const int* src = (const int*)d_in[27];
  float* out = (float*)d_out;

  float* na0_tab = (float*)d_ws;
  float* h_tab = na0_tab + N_NODES * 320;

  node_kernel<<<N_NODES, 192, 0, stream>>>(node_attr, W_inner0, b_inner0, W_inner1,
                                           W_in0, b_in0, W_in1,
                                           gp_W1, gp_b1, gp_W2, gp_b2,
                                           na0_tab, h_tab);
  edge_kernel<<<E_EDGES / TE, 256, 0, stream>>>(edge_attr, node_pair_attr,
                                                fcnp_W1, fcnp_W2,
                                                fcs_W1, fcs_b1, fcs_W2, fcs_b2,
                                                ng_W1, ng_b1, ng_W2, ng_b2,
                                                res_W0, res_b0, res_W1,
                                                dst, src, na0_tab, h_tab, out);
}

// Round 4
// 2077.140 us; speedup vs baseline: 1.7580x; 1.7580x over previous
//
#include <hip/hip_runtime.h>

// PairNetLayer_symmetry, MFMA version. (Resubmission — round 3 hit a broker
// GPUAcquisitionTimeout; no bench data was produced.)
// Stage 1: node_kernel -> f32 tables na0_tab/h_tab (512x320 each) in d_ws.
// Stage 1b: pack_kernel x6 -> bf16 weights, N-major K-contiguous (B-fragment layout).
// Stage 2: edge_kernel: 64 edges/block, 8 waves; all matmuls on v_mfma_f32_16x16x32_bf16.
//   A operand: lane holds row (lane&15), k = 8*(lane>>4)+j (contiguous) from XOR-swizzled LDS.
//   B operand: lane holds col (lane&15), same k pattern, from packed global (L2-resident).
//   C/D: col=lane&15, row=4*(lane>>4)+reg.

#define N_NODES 512
#define E_EDGES 262144
#define TE 64
#define NBLK (E_EDGES / TE)

typedef short bf16x8 __attribute__((ext_vector_type(8)));
typedef float f32x4 __attribute__((ext_vector_type(4)));
#define MFMA16(A, B, C) __builtin_amdgcn_mfma_f32_16x16x32_bf16((A), (B), (C), 0, 0, 0)

__device__ __forceinline__ ushort f2b(float f) {
  unsigned u = __float_as_uint(f);
  unsigned r = (u + 0x7FFFu + ((u >> 16) & 1u)) >> 16;  // RNE; inputs finite
  return (ushort)r;
}
__device__ __forceinline__ float b2f(ushort h) { return __uint_as_float(((unsigned)h) << 16); }
__device__ __forceinline__ float siluf(float x) { return x / (1.f + __expf(-x)); }
__device__ __forceinline__ float sspf(float x) {
  return fmaxf(x, 0.f) + log1pf(__expf(-fabsf(x))) - 0.6931471805599453f;
}

#define RS128 0.08838834764831845f
#define RS192 0.07216878364870323f
#define RS64  0.125f
#define RS32  0.17677669529663687f
#define RS8   0.35355339059327373f
#define RS3   0.5773502691896258f
#define RS2   0.7071067811865476f

// Byte offsets into swizzled LDS buffers.
#define AOFF(e_, c_) (((((e_) << 8) + (c_)) << 1) ^ (((e_) & 7) << 4))   // Ash bf16 [64][256]
#define AOFFF(e_, c_) (((((e_) << 7) + (c_)) << 2) ^ (((e_) & 7) << 4))  // Ash as f32 [64][128]
#define VOFF(i_, e_, u_) (((((i_) << 12) + ((e_) << 6) + (u_)) << 1) ^ (((e_) & 7) << 4))

// ---------------- weight pack: dst[n*K+k] = bf16(W[k*N+n]) ----------------
__global__ void pack_kernel(const float* __restrict__ W, ushort* __restrict__ dst, int K, int N) {
  int idx = blockIdx.x * 256 + threadIdx.x;
  if (idx >= K * N) return;
  int n = idx / K, k = idx - n * K;
  dst[idx] = f2b(W[k * N + n]);
}

// ---------------- node stage (f32, tiny) ----------------
__global__ __launch_bounds__(192) void node_kernel(
    const float* __restrict__ node_attr,
    const float* __restrict__ W_inner0, const float* __restrict__ b_inner0, const float* __restrict__ W_inner1,
    const float* __restrict__ W_in0, const float* __restrict__ b_in0, const float* __restrict__ W_in1,
    const float* __restrict__ gp_W1, const float* __restrict__ gp_b1,
    const float* __restrict__ gp_W2, const float* __restrict__ gp_b2,
    float* __restrict__ na0_tab, float* __restrict__ h_tab)
{
  const int node = blockIdx.x;
  const int t = threadIdx.x;
  __shared__ float x[320];
  __shared__ float cat[192];
  __shared__ float g1[192];
  __shared__ float g[192];
  __shared__ float hh[320];

  for (int i = t; i < 320; i += 192) x[i] = node_attr[node * 320 + i];
  __syncthreads();
  {
    if (t < 128) {
      float acc = 0.f;
      for (int k = 0; k < 128; ++k) acc += x[k] * W_inner0[k * 128 + t];
      na0_tab[node * 320 + t] = acc * RS128 + b_inner0[t];
    }
    int vv = t / 3, ii = t - 3 * vv;
    float acc = 0.f;
    for (int u = 0; u < 64; ++u) acc += x[128 + 3 * u + ii] * W_inner1[u * 64 + vv];
    na0_tab[node * 320 + 128 + t] = acc * RS64;
  }
  if (t < 128) cat[t] = x[t];
  if (t < 64) {
    float a = x[128 + 3 * t], b = x[128 + 3 * t + 1], c = x[128 + 3 * t + 2];
    cat[128 + t] = sqrtf(a * a + b * b + c * c + 1e-12f);
  }
  __syncthreads();
  {
    float acc = 0.f;
    for (int k = 0; k < 192; ++k) acc += cat[k] * gp_W1[k * 192 + t];
    g1[t] = siluf(acc + gp_b1[t]);
  }
  __syncthreads();
  {
    float acc = 0.f;
    for (int k = 0; k < 192; ++k) acc += g1[k] * gp_W2[k * 192 + t];
    g[t] = acc + gp_b2[t];
  }
  __syncthreads();
  if (t < 128) hh[t] = g[t];
  hh[128 + t] = x[128 + t] * g[128 + t / 3];
  __syncthreads();
  {
    if (t < 128) {
      float acc = 0.f;
      for (int k = 0; k < 128; ++k) acc += hh[k] * W_in0[k * 128 + t];
      h_tab[node * 320 + t] = acc * RS128 + b_in0[t];
    }
    int vv = t / 3, ii = t - 3 * vv;
    float acc = 0.f;
    for (int u = 0; u < 64; ++u) acc += hh[128 + 3 * u + ii] * W_in1[u * 64 + vv];
    h_tab[node * 320 + 128 + t] = acc * RS64;
  }
}

// ---------------- edge stage ----------------
__global__ __launch_bounds__(512, 4) void edge_kernel(
    const float* __restrict__ edge_attr, const float* __restrict__ node_pair_attr,
    const float* __restrict__ fcnp_W1, const float* __restrict__ fcnp_W2,
    const float* __restrict__ fcs_b1, const float* __restrict__ fcs_b2,
    const float* __restrict__ ng_b1, const float* __restrict__ ng_b2,
    const float* __restrict__ res_b0,
    const ushort* __restrict__ Wp_fcs1, const ushort* __restrict__ Wp_fcs2,
    const ushort* __restrict__ Wp_ng1, const ushort* __restrict__ Wp_ng2,
    const ushort* __restrict__ Wp_res0, const ushort* __restrict__ Wp_res1,
    const int* __restrict__ dst, const int* __restrict__ src,
    const float* __restrict__ na0_tab, const float* __restrict__ h_tab,
    float* __restrict__ out)
{
  __shared__ ushort Ash[TE * 256];      // 32 KB: s0 -> t1 -> pair_s/cat -> g1 -> pair2_s -> out_s(f32)
  __shared__ ushort Vsh[3 * TE * 64];   // 24 KB: component planes: cross -> pair_v -> pair2_v -> out_v
  __shared__ float pbuf[TE][8];
  __shared__ int di[TE], si[TE];

  const int t = threadIdx.x;
  const int e0 = blockIdx.x * TE;
  const int wid = t >> 6, lane = t & 63, lr = lane & 15, lk = lane >> 4;
  char* ashp = (char*)Ash;
  char* vshp = (char*)Vsh;

  if (t < TE) { di[t] = dst[e0 + t]; si[t] = src[e0 + t]; }
  __syncthreads();

  // ---- P0: pbuf = ssp(edge_attr @ fcnp_W1 * RS32) ----
  {
    int e = t >> 3, m = t & 7;
    const float* ea = edge_attr + (size_t)(e0 + e) * 32;
    float acc = 0.f;
#pragma unroll
    for (int k = 0; k < 32; ++k) acc += ea[k] * fcnp_W1[k * 8 + m];
    pbuf[e][m] = sspf(acc * RS32);
  }
  // ---- P0: s0 -> Ash bf16 cols 0..191 ----
  for (int idx = t; idx < TE * 192; idx += 512) {
    int e = idx / 192, j = idx - e * 192;
    const float* rd = na0_tab + di[e] * 320;
    const float* rs = na0_tab + si[e] * 320;
    float v;
    if (j < 128) v = 0.5f * (rd[j] + rs[j]);
    else {
      int b = 128 + 3 * (j - 128);
      v = (rd[b] * rs[b] + rd[b + 1] * rs[b + 1] + rd[b + 2] * rs[b + 2]) * RS3;
    }
    *(ushort*)(ashp + AOFF(e, j)) = f2b(v);
  }
  __syncthreads();

  // ---- M1: t1 = silu(s0 @ fcs_W1 + b1)  [K=192, N=128, nt=wid] ----
  f32x4 acc1[4];
  {
    int c = (wid << 4) + lr;
    const ushort* bp = Wp_fcs1 + c * 192 + lk * 8;
#pragma unroll
    for (int mt = 0; mt < 4; ++mt) acc1[mt] = (f32x4){0.f, 0.f, 0.f, 0.f};
#pragma unroll
    for (int ks = 0; ks < 6; ++ks) {
      bf16x8 B = *(const bf16x8*)(bp + ks * 32);
#pragma unroll
      for (int mt = 0; mt < 4; ++mt) {
        bf16x8 A = *(const bf16x8*)(ashp + AOFF(mt * 16 + lr, ks * 32 + lk * 8));
        acc1[mt] = MFMA16(A, B, acc1[mt]);
      }
    }
  }
  __syncthreads();
  {
    int c = (wid << 4) + lr;  // < 128
    float b = fcs_b1[c];
#pragma unroll
    for (int mt = 0; mt < 4; ++mt)
#pragma unroll
      for (int r = 0; r < 4; ++r) {
        int e = mt * 16 + lk * 4 + r;
        *(ushort*)(ashp + AOFF(e, c)) = f2b(siluf(acc1[mt][r] + b));
      }
  }
  __syncthreads();

  // ---- M2: w = (t1 @ fcs_W2 + b2) * w_edge  [K=128, N=256, nt={2w,2w+1}] ----
  f32x4 acc2[2][4];
#pragma unroll
  for (int ni = 0; ni < 2; ++ni) {
    int c = ((2 * wid + ni) << 4) + lr;
    const ushort* bp = Wp_fcs2 + c * 128 + lk * 8;
#pragma unroll
    for (int mt = 0; mt < 4; ++mt) acc2[ni][mt] = (f32x4){0.f, 0.f, 0.f, 0.f};
#pragma unroll
    for (int ks = 0; ks < 4; ++ks) {
      bf16x8 B = *(const bf16x8*)(bp + ks * 32);
#pragma unroll
      for (int mt = 0; mt < 4; ++mt) {
        bf16x8 A = *(const bf16x8*)(ashp + AOFF(mt * 16 + lr, ks * 32 + lk * 8));
        acc2[ni][mt] = MFMA16(A, B, acc2[ni][mt]);
      }
    }
  }
  __syncthreads();
  // epilogue: pair construction (w folded in): scalars -> Ash, cross -> Vsh
#pragma unroll
  for (int ni = 0; ni < 2; ++ni) {
    int c = ((2 * wid + ni) << 4) + lr;
    float b = fcs_b2[c];
    float wm[8];
#pragma unroll
    for (int m = 0; m < 8; ++m) wm[m] = fcnp_W2[m * 256 + c] * RS8;
#pragma unroll
    for (int mt = 0; mt < 4; ++mt) {
#pragma unroll
      for (int r = 0; r < 4; ++r) {
        int e = mt * 16 + lk * 4 + r;
        float wv = acc2[ni][mt][r] + b;
        const float4 p0 = *(const float4*)&pbuf[e][0];
        const float4 p1 = *(const float4*)&pbuf[e][4];
        wv *= p0.x * wm[0] + p0.y * wm[1] + p0.z * wm[2] + p0.w * wm[3] +
              p1.x * wm[4] + p1.y * wm[5] + p1.z * wm[6] + p1.w * wm[7];
        const float* hd = h_tab + di[e] * 320;
        const float* hs = h_tab + si[e] * 320;
        if (c < 128) {  // wave-uniform branch (c block-aligned per nt)
          *(ushort*)(ashp + AOFF(e, c)) = f2b(wv * hs[c] * hd[c]);
        } else if (c < 192) {
          int bx = 128 + 3 * (c - 128);
          float dt = hs[bx] * hd[bx] + hs[bx + 1] * hd[bx + 1] + hs[bx + 2] * hd[bx + 2];
          *(ushort*)(ashp + AOFF(e, c)) = f2b(wv * RS3 * dt);
        } else {
          int u = c - 192, bx = 128 + 3 * u;
          float a0 = hs[bx], a1 = hs[bx + 1], a2 = hs[bx + 2];
          float b0 = hd[bx], b1 = hd[bx + 1], b2 = hd[bx + 2];
          float s = wv * RS2;
          *(ushort*)(vshp + VOFF(0, e, u)) = f2b(s * (a1 * b2 - a2 * b1));
          *(ushort*)(vshp + VOFF(1, e, u)) = f2b(s * (a2 * b0 - a0 * b2));
          *(ushort*)(vshp + VOFF(2, e, u)) = f2b(s * (a0 * b1 - a1 * b0));
        }
      }
    }
  }
  __syncthreads();

  // ---- norms -> Ash cols 192..255 (cat complete) ----
  for (int idx = t; idx < TE * 64; idx += 512) {
    int e = idx >> 6, u = idx & 63;
    float v0 = b2f(*(const ushort*)(vshp + VOFF(0, e, u)));
    float v1 = b2f(*(const ushort*)(vshp + VOFF(1, e, u)));
    float v2 = b2f(*(const ushort*)(vshp + VOFF(2, e, u)));
    *(ushort*)(ashp + AOFF(e, 192 + u)) = f2b(sqrtf(v0 * v0 + v1 * v1 + v2 * v2 + 1e-12f));
  }
  __syncthreads();

  // ---- M3: g1 = silu(cat @ ng_W1 + b1)  [K=256, N=256] ----
  f32x4 acc3[2][4];
#pragma unroll
  for (int ni = 0; ni < 2; ++ni) {
    int c = ((2 * wid + ni) << 4) + lr;
    const ushort* bp = Wp_ng1 + c * 256 + lk * 8;
#pragma unroll
    for (int mt = 0; mt < 4; ++mt) acc3[ni][mt] = (f32x4){0.f, 0.f, 0.f, 0.f};
#pragma unroll
    for (int ks = 0; ks < 8; ++ks) {
      bf16x8 B = *(const bf16x8*)(bp + ks * 32);
#pragma unroll
      for (int mt = 0; mt < 4; ++mt) {
        bf16x8 A = *(const bf16x8*)(ashp + AOFF(mt * 16 + lr, ks * 32 + lk * 8));
        acc3[ni][mt] = MFMA16(A, B, acc3[ni][mt]);
      }
    }
  }
  __syncthreads();
#pragma unroll
  for (int ni = 0; ni < 2; ++ni) {
    int c = ((2 * wid + ni) << 4) + lr;
    float b = ng_b1[c];
#pragma unroll
    for (int mt = 0; mt < 4; ++mt)
#pragma unroll
      for (int r = 0; r < 4; ++r) {
        int e = mt * 16 + lk * 4 + r;
        *(ushort*)(ashp + AOFF(e, c)) = f2b(siluf(acc3[ni][mt][r] + b));
      }
  }
  __syncthreads();

  // ---- M4: g = g1 @ ng_W2 + b2 ; pair2 ----
  f32x4 acc4[2][4];
#pragma unroll
  for (int ni = 0; ni < 2; ++ni) {
    int c = ((2 * wid + ni) << 4) + lr;
    const ushort* bp = Wp_ng2 + c * 256 + lk * 8;
#pragma unroll
    for (int mt = 0; mt < 4; ++mt) acc4[ni][mt] = (f32x4){0.f, 0.f, 0.f, 0.f};
#pragma unroll
    for (int ks = 0; ks < 8; ++ks) {
      bf16x8 B = *(const bf16x8*)(bp + ks * 32);
#pragma unroll
      for (int mt = 0; mt < 4; ++mt) {
        bf16x8 A = *(const bf16x8*)(ashp + AOFF(mt * 16 + lr, ks * 32 + lk * 8));
        acc4[ni][mt] = MFMA16(A, B, acc4[ni][mt]);
      }
    }
  }
  __syncthreads();
#pragma unroll
  for (int ni = 0; ni < 2; ++ni) {
    int c = ((2 * wid + ni) << 4) + lr;
    float b = ng_b2[c];
    if (c < 192) {  // pair2_s
#pragma unroll
      for (int mt = 0; mt < 4; ++mt)
#pragma unroll
        for (int r = 0; r < 4; ++r) {
          int e = mt * 16 + lk * 4 + r;
          *(ushort*)(ashp + AOFF(e, c)) = f2b(acc4[ni][mt][r] + b);
        }
    } else {  // gate vector planes in place
      int u = c - 192;
#pragma unroll
      for (int mt = 0; mt < 4; ++mt)
#pragma unroll
        for (int r = 0; r < 4; ++r) {
          int e = mt * 16 + lk * 4 + r;
          float g = acc4[ni][mt][r] + b;
#pragma unroll
          for (int i = 0; i < 3; ++i) {
            ushort* p = (ushort*)(vshp + VOFF(i, e, u));
            *p = f2b(b2f(*p) * g);
          }
        }
    }
  }
  __syncthreads();

  // ---- M5: out_s = pair2_s @ res_W0 * RS192 + b0  [K=192, N=128] ----
  f32x4 acc5[4];
  {
    int c = (wid << 4) + lr;
    const ushort* bp = Wp_res0 + c * 192 + lk * 8;
#pragma unroll
    for (int mt = 0; mt < 4; ++mt) acc5[mt] = (f32x4){0.f, 0.f, 0.f, 0.f};
#pragma unroll
    for (int ks = 0; ks < 6; ++ks) {
      bf16x8 B = *(const bf16x8*)(bp + ks * 32);
#pragma unroll
      for (int mt = 0; mt < 4; ++mt) {
        bf16x8 A = *(const bf16x8*)(ashp + AOFF(mt * 16 + lr, ks * 32 + lk * 8));
        acc5[mt] = MFMA16(A, B, acc5[mt]);
      }
    }
  }
  // ---- M6: out_v = pair2_v(planes) @ res_W1 * RS64  [M=192 (i,e), K=64, N=64] ----
  f32x4 acc6[6];
  {
    int cv = ((wid & 3) << 4) + lr;
    const ushort* bp6 = Wp_res1 + cv * 64 + lk * 8;
    bf16x8 B0 = *(const bf16x8*)(bp6);
    bf16x8 B1 = *(const bf16x8*)(bp6 + 32);
#pragma unroll
    for (int m6 = 0; m6 < 6; ++m6) {
      int mtg = (wid >> 2) * 6 + m6;
      int i = mtg >> 2;
      int e = ((mtg & 3) << 4) + lr;
      f32x4 a = (f32x4){0.f, 0.f, 0.f, 0.f};
      bf16x8 A0 = *(const bf16x8*)(vshp + VOFF(i, e, lk * 8));
      a = MFMA16(A0, B0, a);
      bf16x8 A1 = *(const bf16x8*)(vshp + VOFF(i, e, 32 + lk * 8));
      a = MFMA16(A1, B1, a);
      acc6[m6] = a;
    }
  }
  __syncthreads();
  // epilogues: out_s f32 into Ash, out_v bf16 into Vsh
  {
    int c = (wid << 4) + lr;
    float b = res_b0[c];
#pragma unroll
    for (int mt = 0; mt < 4; ++mt)
#pragma unroll
      for (int r = 0; r < 4; ++r) {
        int e = mt * 16 + lk * 4 + r;
        *(float*)(ashp + AOFFF(e, c)) = acc5[mt][r] * RS192 + b;
      }
  }
  {
    int cv = ((wid & 3) << 4) + lr;
#pragma unroll
    for (int m6 = 0; m6 < 6; ++m6) {
      int mtg = (wid >> 2) * 6 + m6;
      int i = mtg >> 2;
#pragma unroll
      for (int r = 0; r < 4; ++r) {
        int e = ((mtg & 3) << 4) + lk * 4 + r;
        *(ushort*)(vshp + VOFF(i, e, cv)) = f2b(acc6[m6][r] * RS64);
      }
    }
  }
  __syncthreads();

  // ---- final: out = staged + node_pair_attr (coalesced) ----
  for (int idx = t; idx < TE * 320; idx += 512) {
    int e = idx / 320, j = idx - e * 320;
    float v;
    if (j < 128) {
      v = *(const float*)(ashp + AOFFF(e, j));
    } else {
      int cc = j - 128, u = cc / 3, i = cc - 3 * u;
      v = b2f(*(const ushort*)(vshp + VOFF(i, e, u)));
    }
    size_t off = (size_t)(e0 + e) * 320 + j;
    out[off] = v + node_pair_attr[off];
  }
}

extern "C" void kernel_launch(void* const* d_in, const int* in_sizes, int n_in,
                              void* d_out, int out_size, void* d_ws, size_t ws_size,
                              hipStream_t stream) {
  const float* node_attr      = (const float*)d_in[0];
  const float* edge_attr      = (const float*)d_in[1];
  const float* node_pair_attr = (const float*)d_in[2];
  const float* W_inner0 = (const float*)d_in[3];
  const float* b_inner0 = (const float*)d_in[4];
  const float* W_inner1 = (const float*)d_in[5];
  const float* W_in0    = (const float*)d_in[6];
  const float* b_in0    = (const float*)d_in[7];
  const float* W_in1    = (const float*)d_in[8];
  const float* gp_W1    = (const float*)d_in[9];
  const float* gp_b1    = (const float*)d_in[10];
  const float* gp_W2    = (const float*)d_in[11];
  const float* gp_b2    = (const float*)d_in[12];
  const float* fcnp_W1  = (const float*)d_in[13];
  const float* fcnp_W2  = (const float*)d_in[14];
  const float* fcs_W1   = (const float*)d_in[15];
  const float* fcs_b1   = (const float*)d_in[16];
  const float* fcs_W2   = (const float*)d_in[17];
  const float* fcs_b2   = (const float*)d_in[18];
  const float* ng_W1    = (const float*)d_in[19];
  const float* ng_b1    = (const float*)d_in[20];
  const float* ng_W2    = (const float*)d_in[21];
  const float* ng_b2    = (const float*)d_in[22];
  const float* res_W0   = (const float*)d_in[23];
  const float* res_b0   = (const float*)d_in[24];
  const float* res_W1   = (const float*)d_in[25];
  const int* dst = (const int*)d_in[26];
  const int* src = (const int*)d_in[27];
  float* out = (float*)d_out;

  float* na0_tab = (float*)d_ws;
  float* h_tab = na0_tab + N_NODES * 320;
  ushort* wp = (ushort*)(h_tab + N_NODES * 320);
  ushort* Wp_fcs1 = wp;             // [128][192]
  ushort* Wp_fcs2 = wp + 24576;     // [256][128]
  ushort* Wp_ng1  = wp + 57344;     // [256][256]
  ushort* Wp_ng2  = wp + 122880;    // [256][256]
  ushort* Wp_res0 = wp + 188416;    // [128][192]
  ushort* Wp_res1 = wp + 212992;    // [64][64]

  pack_kernel<<<(192 * 128 + 255) / 256, 256, 0, stream>>>(fcs_W1, Wp_fcs1, 192, 128);
  pack_kernel<<<(128 * 256 + 255) / 256, 256, 0, stream>>>(fcs_W2, Wp_fcs2, 128, 256);
  pack_kernel<<<(256 * 256 + 255) / 256, 256, 0, stream>>>(ng_W1, Wp_ng1, 256, 256);
  pack_kernel<<<(256 * 256 + 255) / 256, 256, 0, stream>>>(ng_W2, Wp_ng2, 256, 256);
  pack_kernel<<<(192 * 128 + 255) / 256, 256, 0, stream>>>(res_W0, Wp_res0, 192, 128);
  pack_kernel<<<(64 * 64 + 255) / 256, 256, 0, stream>>>(res_W1, Wp_res1, 64, 64);

  node_kernel<<<N_NODES, 192, 0, stream>>>(node_attr, W_inner0, b_inner0, W_inner1,
                                           W_in0, b_in0, W_in1,
                                           gp_W1, gp_b1, gp_W2, gp_b2,
                                           na0_tab, h_tab);
  edge_kernel<<<NBLK, 512, 0, stream>>>(edge_attr, node_pair_attr,
                                        fcnp_W1, fcnp_W2,
                                        fcs_b1, fcs_b2, ng_b1, ng_b2, res_b0,
                                        Wp_fcs1, Wp_fcs2, Wp_ng1, Wp_ng2, Wp_res0, Wp_res1,
                                        dst, src, na0_tab, h_tab, out);
}